// Round 9
// baseline (151.064 us; speedup 1.0000x reference)
//
#include <hip/hip_runtime.h>

typedef unsigned short u16;
typedef unsigned long long u64;
typedef __bf16 bf16x8 __attribute__((ext_vector_type(8)));
typedef float f32x4 __attribute__((ext_vector_type(4)));
typedef int i32x4 __attribute__((ext_vector_type(4)));

#define MFMA16(a, b, c) __builtin_amdgcn_mfma_f32_16x16x32_bf16((a), (b), (c), 0, 0, 0)

__device__ __forceinline__ bf16x8 ld8(const u16* p) {
    return *reinterpret_cast<const bf16x8*>(p);
}

__device__ __forceinline__ unsigned pk2(float a, float b) {
    unsigned short ua = __builtin_bit_cast(unsigned short, (__bf16)a);
    unsigned short ub = __builtin_bit_cast(unsigned short, (__bf16)b);
    return (unsigned)ua | ((unsigned)ub << 16);
}

__device__ __forceinline__ bf16x8 cvt8(f32x4 a, f32x4 b) {
    bf16x8 r;
    r[0] = (__bf16)a[0]; r[1] = (__bf16)a[1]; r[2] = (__bf16)a[2]; r[3] = (__bf16)a[3];
    r[4] = (__bf16)b[0]; r[5] = (__bf16)b[1]; r[6] = (__bf16)b[2]; r[7] = (__bf16)b[3];
    return r;
}

__device__ __forceinline__ f32x4 ntf4(const float* p) {
    return __builtin_nontemporal_load(reinterpret_cast<const f32x4*>(p));
}
__device__ __forceinline__ i32x4 nti4(const int* p) {
    return __builtin_nontemporal_load(reinterpret_cast<const i32x4*>(p));
}

// ---------------- Kernel 0: convert Wq/Wk/Wv fp32 -> bf16 ----------------
__global__ __launch_bounds__(256) void wcvt_kernel(
    const float* __restrict__ Wq, const float* __restrict__ Wk,
    const float* __restrict__ Wv, u16* __restrict__ wb)
{
    const int t = blockIdx.x * 256 + threadIdx.x;
    const int mat = t >> 13;
    const int idx = (t & 8191) * 8;
    const float* src = (mat == 0) ? Wq : (mat == 1) ? Wk : Wv;
    const f32x4 a = *(const f32x4*)(src + idx);
    const f32x4 b = *(const f32x4*)(src + idx + 4);
    uint4 o;
    o.x = pk2(a[0], a[1]); o.y = pk2(a[2], a[3]);
    o.z = pk2(b[0], b[1]); o.w = pk2(b[2], b[3]);
    *reinterpret_cast<uint4*>(wb + (size_t)mat * 65536 + idx) = o;
}

// ---- Kernel 1: FUSED split-K proj (blocks 0..767) + minimal-wave pack (768..8959) ----
__global__ __launch_bounds__(256) void fused_kernel(
    const float* __restrict__ Q, const float* __restrict__ K, const float* __restrict__ V,
    const u16* __restrict__ wb, const int* __restrict__ mask,
    float* __restrict__ pws, u64* __restrict__ bits)
{
    const int lane = threadIdx.x & 63, w = threadIdx.x >> 6;

    if (blockIdx.x >= 768) {
        // ===== pack: wave = one 1KB window per iter, 4 sequential iters =====
        const int gw = (blockIdx.x - 768) * 4 + w;          // 0..32767
        const int* mp = mask + (size_t)gw * 1024 + lane * 4;
        u64* op = bits + (size_t)gw * 16;

        i32x4 cur = nti4(mp);
        #pragma unroll
        for (int i = 0; i < 4; ++i) {
            const i32x4 m4 = cur;
            if (i < 3) cur = nti4(mp + (i + 1) * 256);       // depth-2 pipeline
            // converged ballots; bits[row][j][e]: bit l = mask[row][256j + 4l + e]
            const u64 b0 = __ballot(m4[0] != 0);
            const u64 b1 = __ballot(m4[1] != 0);
            const u64 b2 = __ballot(m4[2] != 0);
            const u64 b3 = __ballot(m4[3] != 0);
            u64 myb = b0;
            if (lane == 1) myb = b1;
            if (lane == 2) myb = b2;
            if (lane == 3) myb = b3;
            if (lane < 4) op[i * 4 + lane] = myb;
        }
        return;
    }

    // ===== proj, split-K x2: block = (mat, tile, ks); wave = 16 rows x 512 K =====
    const int mat  = blockIdx.x / 256;
    const int rem  = blockIdx.x & 255;
    const int tile = rem >> 1;
    const int ks   = rem & 1;
    const int c = lane & 15, g = lane >> 4;

    const float* X = (mat == 0) ? Q : (mat == 1) ? K : V;
    const u16*   W = wb + (size_t)mat * 65536;

    const int rw = tile * 64 + w * 16;
    const float* xp = X + (size_t)(rw + c) * 1024 + ks * 512 + g * 8;
    const u16*   wp = W + (size_t)c * 1024 + ks * 512 + g * 8;

    f32x4 acc[4] = {};
    f32x4 A[4], B[4];                                        // depth-4 ring (static idx)
    #pragma unroll
    for (int j = 0; j < 4; ++j) {
        A[j] = ntf4(xp + j * 32);
        B[j] = ntf4(xp + j * 32 + 4);
    }

    #pragma unroll
    for (int kk = 0; kk < 16; ++kk) {
        const bf16x8 a = cvt8(A[kk & 3], B[kk & 3]);
        if (kk < 12) {
            A[kk & 3] = ntf4(xp + (kk + 4) * 32);
            B[kk & 3] = ntf4(xp + (kk + 4) * 32 + 4);
        }
        const u16* wk = wp + kk * 32;
        if (mat < 2) {
            // D[row = X-row (g*4+r)][col = dk (t*16+c)]
            #pragma unroll
            for (int t = 0; t < 4; ++t)
                acc[t] = MFMA16(a, ld8(wk + t * 16384), acc[t]);
        } else {
            // SWAPPED for V: D[row = dv (t*16+g*4+r)][col = s (rw+c)]
            // (this swap was dropped in R8 -- that was the correctness bug)
            #pragma unroll
            for (int t = 0; t < 4; ++t)
                acc[t] = MFMA16(ld8(wk + t * 16384), a, acc[t]);
        }
    }

    // partials: pws[wave*2048 + idx*2 + ks], idx = t*256 + (g*4+r)*16 + c
    //   mat<2 : (g*4+r) = row-within-16, c = col-within-16
    //   mat==2: (g*4+r) = dv-within-16,  c = s-within-16   (swapped convention)
    const size_t wave = (size_t)((mat * 128 + tile) * 4 + w);
    float* pp = pws + wave * 2048 + ks;
    #pragma unroll
    for (int t = 0; t < 4; ++t) {
        #pragma unroll
        for (int r = 0; r < 4; ++r)
            pp[(t * 256 + (g * 4 + r) * 16 + c) * 2] = acc[t][r];
    }
}

// ---- Kernel 2: reduce split-K partials + bias -> qb, kb (row-major), vtb (transposed) ----
__global__ __launch_bounds__(256) void projred_kernel(
    const float* __restrict__ pws,
    const float* __restrict__ bq, const float* __restrict__ bk, const float* __restrict__ bv,
    u16* __restrict__ qb, u16* __restrict__ kb, u16* __restrict__ vtb)
{
    const int tid = blockIdx.x * 256 + threadIdx.x;          // 1,572,864 total
    const int wave = tid >> 10;
    const int idx  = tid & 1023;                             // t*256 + row16*16 + c
    const int t = idx >> 8, row16 = (idx >> 4) & 15, c = idx & 15;
    const int mat  = wave >> 9;
    const int tile = (wave >> 2) & 127;
    const int w    = wave & 3;
    const int rw   = tile * 64 + w * 16;

    const float sum = pws[tid * 2] + pws[tid * 2 + 1];

    if (mat < 2) {
        const float* bias = (mat == 0) ? bq : bk;
        u16* dst = (mat == 0) ? qb : kb;
        const int row = rw + row16;
        dst[(size_t)row * 64 + t * 16 + c] =
            __builtin_bit_cast(u16, (__bf16)(sum + bias[t * 16 + c]));
    } else {
        const int dv = t * 16 + row16;
        const int sg = rw + c;
        vtb[(size_t)((sg >> 12) * 64 + dv) * 4096 + (sg & 4095)] =
            __builtin_bit_cast(u16, (__bf16)(sum + bv[dv]));
    }
}

// ---------------- Kernel 3: flash attention phase 1 (unchanged) ----------------
__global__ __launch_bounds__(256) void attn_kernel(
    const u64* __restrict__ bits, const u16* __restrict__ qb,
    const u16* __restrict__ kb, const u16* __restrict__ vtb,
    float* __restrict__ pacc, float* __restrict__ pm, float* __restrict__ pl)
{
    __shared__ uint2 plds[4][128];   // per-wave 16q x 32s bf16, XOR-swizzled
    const int lane = threadIdx.x & 63, w = threadIdx.x >> 6;
    const int c = lane & 15, g = lane >> 4;
    const int gw    = blockIdx.x * 4 + w;
    const int strip = gw >> 3;
    const int chunk = gw & 7;
    const int b     = strip >> 8;
    const int q0    = (strip & 255) * 16;
    const int sBase = chunk * 512;
    const float SSC = 0.18033688011112042f;   // (1/8) * log2(e)

    const u16* qrow = qb + (size_t)((b << 12) + q0 + c) * 64 + g * 8;
    const bf16x8 qf0 = ld8(qrow);
    const bf16x8 qf1 = ld8(qrow + 32);

    const u16* kfp = kb  + (((size_t)b << 12) + sBase + c) * 64 + g * 8;
    const u16* vfp = vtb + (size_t)(b * 64 + c) * 4096 + sBase + g * 8;

    const u64* bp = bits + (size_t)((b << 12) + q0 + c) * 64 + chunk * 8;
    const u64 Wd0 = bp[0], Wd1 = bp[1], Wd2 = bp[2], Wd3 = bp[3];
    const u64 Wd4 = bp[4], Wd5 = bp[5], Wd6 = bp[6], Wd7 = bp[7];

    f32x4 acc0 = {}, acc1 = {}, acc2 = {}, acc3 = {};
    const f32x4 zf = {};
    float m_run = -__builtin_inff(), l_run = 0.f;

    bf16x8 k00 = ld8(kfp),            k01 = ld8(kfp + 32);
    bf16x8 k10 = ld8(kfp + 16 * 64),  k11 = ld8(kfp + 16 * 64 + 32);

    #pragma unroll
    for (int half = 0; half < 2; ++half) {
        const u64 Wr0 = half ? Wd4 : Wd0;
        const u64 Wr1 = half ? Wd5 : Wd1;
        const u64 Wr2 = half ? Wd6 : Wd2;
        const u64 Wr3 = half ? Wd7 : Wd3;
        #pragma unroll 1
        for (int it2 = 0; it2 < 8; ++it2) {
            const int it = half * 8 + it2;

            const u16* vp = vfp + it * 32;
            const bf16x8 v0 = ld8(vp);
            const bf16x8 v1 = ld8(vp + 16 * 4096);
            const bf16x8 v2 = ld8(vp + 32 * 4096);
            const bf16x8 v3 = ld8(vp + 48 * 4096);

            f32x4 d0 = MFMA16(k00, qf0, zf);
            d0 = MFMA16(k01, qf1, d0);
            f32x4 d1 = MFMA16(k10, qf0, zf);
            d1 = MFMA16(k11, qf1, d1);

            const int no = (it < 15) ? (it + 1) * 2048 : it * 2048;
            k00 = ld8(kfp + no);            k01 = ld8(kfp + no + 32);
            k10 = ld8(kfp + no + 16 * 64);  k11 = ld8(kfp + no + 16 * 64 + 32);

            const int sh = it2 * 8 + g;
            const unsigned t0 = (unsigned)(Wr0 >> sh);
            const unsigned t1 = (unsigned)(Wr1 >> sh);
            const unsigned t2 = (unsigned)(Wr2 >> sh);
            const unsigned t3 = (unsigned)(Wr3 >> sh);

            const float x0 = (t0 & 1u)  ? d0[0] * SSC : -1e9f;
            const float x1 = (t1 & 1u)  ? d0[1] * SSC : -1e9f;
            const float x2 = (t2 & 1u)  ? d0[2] * SSC : -1e9f;
            const float x3 = (t3 & 1u)  ? d0[3] * SSC : -1e9f;
            const float x4 = (t0 & 16u) ? d1[0] * SSC : -1e9f;
            const float x5 = (t1 & 16u) ? d1[1] * SSC : -1e9f;
            const float x6 = (t2 & 16u) ? d1[2] * SSC : -1e9f;
            const float x7 = (t3 & 16u) ? d1[3] * SSC : -1e9f;

            float tm = fmaxf(fmaxf(fmaxf(x0, x1), fmaxf(x2, x3)),
                             fmaxf(fmaxf(x4, x5), fmaxf(x6, x7)));
            tm = fmaxf(tm, __shfl_xor(tm, 16));
            tm = fmaxf(tm, __shfl_xor(tm, 32));
            const float m_new = fmaxf(m_run, tm);
            const float f = exp2f(m_run - m_new);

            const float p0 = exp2f(x0 - m_new), p1 = exp2f(x1 - m_new);
            const float p2 = exp2f(x2 - m_new), p3 = exp2f(x3 - m_new);
            const float p4 = exp2f(x4 - m_new), p5 = exp2f(x5 - m_new);
            const float p6 = exp2f(x6 - m_new), p7 = exp2f(x7 - m_new);
            float rs = ((p0 + p1) + (p2 + p3)) + ((p4 + p5) + (p6 + p7));
            rs += __shfl_xor(rs, 16);
            rs += __shfl_xor(rs, 32);
            l_run = l_run * f + rs;
            m_run = m_new;

            plds[w][c * 8 + ( g      ^ (c & 7))] = make_uint2(pk2(p0, p1), pk2(p2, p3));
            plds[w][c * 8 + ((g + 4) ^ (c & 7))] = make_uint2(pk2(p4, p5), pk2(p6, p7));

            if (__any(f < 1.0f)) {
                const float f0 = __shfl(f, g * 4 + 0);
                const float f1 = __shfl(f, g * 4 + 1);
                const float f2 = __shfl(f, g * 4 + 2);
                const float f3 = __shfl(f, g * 4 + 3);
                acc0[0] *= f0; acc0[1] *= f1; acc0[2] *= f2; acc0[3] *= f3;
                acc1[0] *= f0; acc1[1] *= f1; acc1[2] *= f2; acc1[3] *= f3;
                acc2[0] *= f0; acc2[1] *= f1; acc2[2] *= f2; acc2[3] *= f3;
                acc3[0] *= f0; acc3[1] *= f1; acc3[2] *= f2; acc3[3] *= f3;
            }

            union { uint2 u[2]; bf16x8 v; } pa;
            pa.u[0] = plds[w][c * 8 + ((2 * g    ) ^ (c & 7))];
            pa.u[1] = plds[w][c * 8 + ((2 * g + 1) ^ (c & 7))];

            acc0 = MFMA16(pa.v, v0, acc0);
            acc1 = MFMA16(pa.v, v1, acc1);
            acc2 = MFMA16(pa.v, v2, acc2);
            acc3 = MFMA16(pa.v, v3, acc3);
        }
    }

    const size_t pidx = (size_t)(strip * 8 + chunk) * 16;
    #pragma unroll
    for (int r = 0; r < 4; ++r) {
        const size_t row = pidx + g * 4 + r;
        pacc[row * 64 +  0 + c] = acc0[r];
        pacc[row * 64 + 16 + c] = acc1[r];
        pacc[row * 64 + 32 + c] = acc2[r];
        pacc[row * 64 + 48 + c] = acc3[r];
    }
    if (lane < 16) {
        pm[pidx + c] = m_run;
        pl[pidx + c] = l_run;
    }
}

// ---------------- Kernel 4: combine 8 s-chunk partials per row ----------------
__global__ __launch_bounds__(256) void comb_kernel(
    const float* __restrict__ pacc, const float* __restrict__ pm,
    const float* __restrict__ pl, float* __restrict__ out)
{
    const int t = blockIdx.x * 256 + threadIdx.x;
    const int r = t >> 6, dv = t & 63;
    const int strip = r >> 4, qi = r & 15;
    const int base = strip * 128 + qi;
    float mv[8];
    float M = -__builtin_inff();
    #pragma unroll
    for (int cc = 0; cc < 8; ++cc) { mv[cc] = pm[base + cc * 16]; M = fmaxf(M, mv[cc]); }
    float num = 0.f, den = 0.f;
    #pragma unroll
    for (int cc = 0; cc < 8; ++cc) {
        const float wgt = exp2f(mv[cc] - M);
        num += wgt * pacc[(size_t)(base + cc * 16) * 64 + dv];
        den += wgt * pl[base + cc * 16];
    }
    out[t] = num / den;
}

extern "C" void kernel_launch(void* const* d_in, const int* in_sizes, int n_in,
                              void* d_out, int out_size, void* d_ws, size_t ws_size,
                              hipStream_t stream)
{
    const float* Q    = (const float*)d_in[0];
    const float* K    = (const float*)d_in[1];
    const float* V    = (const float*)d_in[2];
    const int*   mask = (const int*)d_in[3];
    const float* Wq   = (const float*)d_in[4];
    const float* bq   = (const float*)d_in[5];
    const float* Wk   = (const float*)d_in[6];
    const float* bk   = (const float*)d_in[7];
    const float* Wv   = (const float*)d_in[8];
    const float* bv   = (const float*)d_in[9];
    float* out = (float*)d_out;

    char* ws = (char*)d_ws;
    u16*   wb   = (u16*)(ws);                            // 384 KB
    u16*   qb   = (u16*)(ws + 393216);                   // 1 MB
    u16*   kb   = (u16*)(ws + 393216 + 1048576);         // 1 MB
    u16*   vtb  = (u16*)(ws + 393216 + 2097152);         // 1 MB
    u64*   bits = (u64*)(ws + 4194304);                  // 4 MB: [8192][16][4] u64
    float* pm   = (float*)(ws + 8388608);                // 256 KB
    float* pl   = (float*)(ws + 8388608 + 262144);       // 256 KB
    float* pacc = (float*)(ws + 8388608 + 524288);       // 16 MB
    float* pws  = (float*)(ws + 8388608 + 524288 + 16777216);  // 12.6 MB split-K partials

    wcvt_kernel<<<96, 256, 0, stream>>>(Wq, Wk, Wv, wb);
    fused_kernel<<<8960, 256, 0, stream>>>(Q, K, V, wb, mask, pws, bits);
    projred_kernel<<<6144, 256, 0, stream>>>(pws, bq, bk, bv, qb, kb, vtb);
    attn_kernel<<<1024, 256, 0, stream>>>(bits, qb, kb, vtb, pacc, pm, pl);
    comb_kernel<<<2048, 256, 0, stream>>>(pacc, pm, pl, out);
}

// Round 11
// 133.781 us; speedup vs baseline: 1.1292x; 1.1292x over previous
//
#include <hip/hip_runtime.h>

typedef unsigned short u16;
typedef unsigned long long u64;
typedef __bf16 bf16x8 __attribute__((ext_vector_type(8)));
typedef float f32x4 __attribute__((ext_vector_type(4)));
typedef int i32x4 __attribute__((ext_vector_type(4)));

#define MFMA16(a, b, c) __builtin_amdgcn_mfma_f32_16x16x32_bf16((a), (b), (c), 0, 0, 0)

__device__ __forceinline__ bf16x8 ld8(const u16* p) {
    return *reinterpret_cast<const bf16x8*>(p);
}

__device__ __forceinline__ unsigned pk2(float a, float b) {
    unsigned short ua = __builtin_bit_cast(unsigned short, (__bf16)a);
    unsigned short ub = __builtin_bit_cast(unsigned short, (__bf16)b);
    return (unsigned)ua | ((unsigned)ub << 16);
}

__device__ __forceinline__ f32x4 ntf4(const float* p) {
    return __builtin_nontemporal_load(reinterpret_cast<const f32x4*>(p));
}
__device__ __forceinline__ i32x4 nti4(const int* p) {
    return __builtin_nontemporal_load(reinterpret_cast<const i32x4*>(p));
}

// ---------------- Kernel 0: convert Wq/Wk/Wv fp32 -> bf16 ----------------
__global__ __launch_bounds__(256) void wcvt_kernel(
    const float* __restrict__ Wq, const float* __restrict__ Wk,
    const float* __restrict__ Wv, u16* __restrict__ wb)
{
    const int t = blockIdx.x * 256 + threadIdx.x;
    const int mat = t >> 13;
    const int idx = (t & 8191) * 8;
    const float* src = (mat == 0) ? Wq : (mat == 1) ? Wk : Wv;
    const f32x4 a = *(const f32x4*)(src + idx);
    const f32x4 b = *(const f32x4*)(src + idx + 4);
    uint4 o;
    o.x = pk2(a[0], a[1]); o.y = pk2(a[2], a[3]);
    o.z = pk2(b[0], b[1]); o.w = pk2(b[2], b[3]);
    *reinterpret_cast<uint4*>(wb + (size_t)mat * 65536 + idx) = o;
}

// ---- Kernel 1: FUSED contiguous-front proj (blocks 0..1535) + pack (1536..3583) ----
// proj: block = 16 X-rows = contiguous 64KB; stage->LDS(bf16,swizzled)->sync->MFMA.
// pack: R7-verified converged-ballot bitpack, VGPR only.
__global__ __launch_bounds__(256) void fused_kernel(
    const float* __restrict__ Q, const float* __restrict__ K, const float* __restrict__ V,
    const float* __restrict__ bq, const float* __restrict__ bk, const float* __restrict__ bv,
    const u16* __restrict__ wb, const int* __restrict__ mask,
    u16* __restrict__ qb, u16* __restrict__ kb, u16* __restrict__ vtb,
    u64* __restrict__ bits)
{
    __shared__ uint2 xlds[16][256];     // 32 KB: 16 rows x 1024 bf16, 16B-granule XOR swizzle
    const int lane = threadIdx.x & 63, w = threadIdx.x >> 6;

    if (blockIdx.x >= 1536) {
        // ======== mask bitpack: one wave per row, 16 int4 loads up-front ========
        const int row = (blockIdx.x - 1536) * 4 + w;         // 0..8191
        const int* mp = mask + (size_t)row * 4096 + lane * 4;
        u64* op = bits + (size_t)row * 64;

        i32x4 h0[8], h1[8];                                  // 16 KB/wave in flight
        #pragma unroll
        for (int j = 0; j < 8; ++j) h0[j] = nti4(mp + j * 256);
        #pragma unroll
        for (int j = 0; j < 8; ++j) h1[j] = nti4(mp + 2048 + j * 256);

        u64 mine0 = 0, mine1 = 0;
        #pragma unroll
        for (int j = 0; j < 8; ++j) {
            // all ballots fully converged; per-lane keep is register select
            const u64 b0 = __ballot(h0[j][0] != 0);
            const u64 b1 = __ballot(h0[j][1] != 0);
            const u64 b2 = __ballot(h0[j][2] != 0);
            const u64 b3 = __ballot(h0[j][3] != 0);
            if (lane == j * 4 + 0) mine0 = b0;
            if (lane == j * 4 + 1) mine0 = b1;
            if (lane == j * 4 + 2) mine0 = b2;
            if (lane == j * 4 + 3) mine0 = b3;
            const u64 c0 = __ballot(h1[j][0] != 0);
            const u64 c1 = __ballot(h1[j][1] != 0);
            const u64 c2 = __ballot(h1[j][2] != 0);
            const u64 c3 = __ballot(h1[j][3] != 0);
            if (lane == j * 4 + 0) mine1 = c0;
            if (lane == j * 4 + 1) mine1 = c1;
            if (lane == j * 4 + 2) mine1 = c2;
            if (lane == j * 4 + 3) mine1 = c3;
        }
        // layout: bits[row][j=0..15][e=0..3], bit l = mask[row][256j + 4l + e]
        if (lane < 32) { op[lane] = mine0; op[32 + lane] = mine1; }
        return;                      // block-uniform early exit (no sync in this branch)
    }

    // ======== projections: block = 16 rows, CONTIGUOUS 64KB staging ========
    const int mat  = blockIdx.x >> 9;                        // 0=q 1=k 2=v
    const int tile = blockIdx.x & 511;
    const int r0   = tile * 16;
    const int t    = threadIdx.x;
    const float* X = (mat == 0) ? Q : (mat == 1) ? K : V;

    // 16 back-to-back nt f32x4 loads: block front = contiguous 64KB (fill-like)
    f32x4 st[16];
    const float* xp = X + (size_t)r0 * 1024 + t * 4;
    #pragma unroll
    for (int i = 0; i < 16; ++i) st[i] = ntf4(xp + i * 1024);

    // cvt fp32->bf16, swizzled LDS write: 16B-granule j of row i at (j ^ (i&7))
    #pragma unroll
    for (int i = 0; i < 16; ++i) {
        xlds[i][(((t >> 1) ^ (i & 7)) << 1) | (t & 1)] =
            make_uint2(pk2(st[i][0], st[i][1]), pk2(st[i][2], st[i][3]));
    }
    __syncthreads();

    const int c = lane & 15, g = lane >> 4;
    // wave w owns output cols (q/k: dk) / rows (v: dv) w*16..w*16+15.
    // W fragment address is identical for both operand orders (verified R1-R7).
    const u16* wp = wb + (size_t)mat * 65536 + (size_t)(w * 16 + c) * 1024 + g * 8;

    f32x4 acc = {};
    #pragma unroll
    for (int kk = 0; kk < 32; ++kk) {
        // A-frag: X row c, K slice kk*32+g*8..+7 = granule kk*4+g, XOR-swizzled
        const bf16x8 a = ld8((const u16*)&xlds[c][((kk * 4 + g) ^ (c & 7)) << 1]);
        const bf16x8 wf = ld8(wp + kk * 32);
        if (mat < 2) acc = MFMA16(a, wf, acc);   // D[row=X-row g*4+r][col=dk w*16+c]
        else         acc = MFMA16(wf, a, acc);   // D[row=dv w*16+g*4+r][col=s r0+c]
    }

    if (mat < 2) {
        const float* bias = (mat == 0) ? bq : bk;
        u16* dst = (mat == 0) ? qb : kb;
        const float bz = bias[w * 16 + c];
        #pragma unroll
        for (int r = 0; r < 4; ++r) {
            dst[(size_t)(r0 + g * 4 + r) * 64 + w * 16 + c] =
                __builtin_bit_cast(u16, (__bf16)(acc[r] + bz));
        }
    } else {
        const int sg = r0 + c;
        const int bidx = sg >> 12, sin = sg & 4095;
        #pragma unroll
        for (int r = 0; r < 4; ++r) {
            const int dv = w * 16 + g * 4 + r;
            vtb[(size_t)(bidx * 64 + dv) * 4096 + sin] =
                __builtin_bit_cast(u16, (__bf16)(acc[r] + bv[dv]));
        }
    }
}

// ---------------- Kernel 2: flash attention phase 1 (unchanged, proven) ----------------
__global__ __launch_bounds__(256) void attn_kernel(
    const u64* __restrict__ bits, const u16* __restrict__ qb,
    const u16* __restrict__ kb, const u16* __restrict__ vtb,
    float* __restrict__ pacc, float* __restrict__ pm, float* __restrict__ pl)
{
    __shared__ uint2 plds[4][128];   // per-wave 16q x 32s bf16, XOR-swizzled
    const int lane = threadIdx.x & 63, w = threadIdx.x >> 6;
    const int c = lane & 15, g = lane >> 4;
    const int gw    = blockIdx.x * 4 + w;
    const int strip = gw >> 3;
    const int chunk = gw & 7;
    const int b     = strip >> 8;
    const int q0    = (strip & 255) * 16;
    const int sBase = chunk * 512;
    const float SSC = 0.18033688011112042f;   // (1/8) * log2(e)

    const u16* qrow = qb + (size_t)((b << 12) + q0 + c) * 64 + g * 8;
    const bf16x8 qf0 = ld8(qrow);
    const bf16x8 qf1 = ld8(qrow + 32);

    const u16* kfp = kb  + (((size_t)b << 12) + sBase + c) * 64 + g * 8;
    const u16* vfp = vtb + (size_t)(b * 64 + c) * 4096 + sBase + g * 8;

    const u64* bp = bits + (size_t)((b << 12) + q0 + c) * 64 + chunk * 8;
    const u64 Wd0 = bp[0], Wd1 = bp[1], Wd2 = bp[2], Wd3 = bp[3];
    const u64 Wd4 = bp[4], Wd5 = bp[5], Wd6 = bp[6], Wd7 = bp[7];

    f32x4 acc0 = {}, acc1 = {}, acc2 = {}, acc3 = {};
    const f32x4 zf = {};
    float m_run = -__builtin_inff(), l_run = 0.f;

    bf16x8 k00 = ld8(kfp),            k01 = ld8(kfp + 32);
    bf16x8 k10 = ld8(kfp + 16 * 64),  k11 = ld8(kfp + 16 * 64 + 32);

    #pragma unroll
    for (int half = 0; half < 2; ++half) {
        const u64 Wr0 = half ? Wd4 : Wd0;
        const u64 Wr1 = half ? Wd5 : Wd1;
        const u64 Wr2 = half ? Wd6 : Wd2;
        const u64 Wr3 = half ? Wd7 : Wd3;
        #pragma unroll 1
        for (int it2 = 0; it2 < 8; ++it2) {
            const int it = half * 8 + it2;

            const u16* vp = vfp + it * 32;
            const bf16x8 v0 = ld8(vp);
            const bf16x8 v1 = ld8(vp + 16 * 4096);
            const bf16x8 v2 = ld8(vp + 32 * 4096);
            const bf16x8 v3 = ld8(vp + 48 * 4096);

            f32x4 d0 = MFMA16(k00, qf0, zf);
            d0 = MFMA16(k01, qf1, d0);
            f32x4 d1 = MFMA16(k10, qf0, zf);
            d1 = MFMA16(k11, qf1, d1);

            const int no = (it < 15) ? (it + 1) * 2048 : it * 2048;
            k00 = ld8(kfp + no);            k01 = ld8(kfp + no + 32);
            k10 = ld8(kfp + no + 16 * 64);  k11 = ld8(kfp + no + 16 * 64 + 32);

            const int sh = it2 * 8 + g;
            const unsigned t0 = (unsigned)(Wr0 >> sh);
            const unsigned t1 = (unsigned)(Wr1 >> sh);
            const unsigned t2 = (unsigned)(Wr2 >> sh);
            const unsigned t3 = (unsigned)(Wr3 >> sh);

            const float x0 = (t0 & 1u)  ? d0[0] * SSC : -1e9f;
            const float x1 = (t1 & 1u)  ? d0[1] * SSC : -1e9f;
            const float x2 = (t2 & 1u)  ? d0[2] * SSC : -1e9f;
            const float x3 = (t3 & 1u)  ? d0[3] * SSC : -1e9f;
            const float x4 = (t0 & 16u) ? d1[0] * SSC : -1e9f;
            const float x5 = (t1 & 16u) ? d1[1] * SSC : -1e9f;
            const float x6 = (t2 & 16u) ? d1[2] * SSC : -1e9f;
            const float x7 = (t3 & 16u) ? d1[3] * SSC : -1e9f;

            float tm = fmaxf(fmaxf(fmaxf(x0, x1), fmaxf(x2, x3)),
                             fmaxf(fmaxf(x4, x5), fmaxf(x6, x7)));
            tm = fmaxf(tm, __shfl_xor(tm, 16));
            tm = fmaxf(tm, __shfl_xor(tm, 32));
            const float m_new = fmaxf(m_run, tm);
            const float f = exp2f(m_run - m_new);

            const float p0 = exp2f(x0 - m_new), p1 = exp2f(x1 - m_new);
            const float p2 = exp2f(x2 - m_new), p3 = exp2f(x3 - m_new);
            const float p4 = exp2f(x4 - m_new), p5 = exp2f(x5 - m_new);
            const float p6 = exp2f(x6 - m_new), p7 = exp2f(x7 - m_new);
            float rs = ((p0 + p1) + (p2 + p3)) + ((p4 + p5) + (p6 + p7));
            rs += __shfl_xor(rs, 16);
            rs += __shfl_xor(rs, 32);
            l_run = l_run * f + rs;
            m_run = m_new;

            plds[w][c * 8 + ( g      ^ (c & 7))] = make_uint2(pk2(p0, p1), pk2(p2, p3));
            plds[w][c * 8 + ((g + 4) ^ (c & 7))] = make_uint2(pk2(p4, p5), pk2(p6, p7));

            if (__any(f < 1.0f)) {
                const float f0 = __shfl(f, g * 4 + 0);
                const float f1 = __shfl(f, g * 4 + 1);
                const float f2 = __shfl(f, g * 4 + 2);
                const float f3 = __shfl(f, g * 4 + 3);
                acc0[0] *= f0; acc0[1] *= f1; acc0[2] *= f2; acc0[3] *= f3;
                acc1[0] *= f0; acc1[1] *= f1; acc1[2] *= f2; acc1[3] *= f3;
                acc2[0] *= f0; acc2[1] *= f1; acc2[2] *= f2; acc2[3] *= f3;
                acc3[0] *= f0; acc3[1] *= f1; acc3[2] *= f2; acc3[3] *= f3;
            }

            union { uint2 u[2]; bf16x8 v; } pa;
            pa.u[0] = plds[w][c * 8 + ((2 * g    ) ^ (c & 7))];
            pa.u[1] = plds[w][c * 8 + ((2 * g + 1) ^ (c & 7))];

            acc0 = MFMA16(pa.v, v0, acc0);
            acc1 = MFMA16(pa.v, v1, acc1);
            acc2 = MFMA16(pa.v, v2, acc2);
            acc3 = MFMA16(pa.v, v3, acc3);
        }
    }

    const size_t pidx = (size_t)(strip * 8 + chunk) * 16;
    #pragma unroll
    for (int r = 0; r < 4; ++r) {
        const size_t row = pidx + g * 4 + r;
        pacc[row * 64 +  0 + c] = acc0[r];
        pacc[row * 64 + 16 + c] = acc1[r];
        pacc[row * 64 + 32 + c] = acc2[r];
        pacc[row * 64 + 48 + c] = acc3[r];
    }
    if (lane < 16) {
        pm[pidx + c] = m_run;
        pl[pidx + c] = l_run;
    }
}

// ---------------- Kernel 3: combine 8 s-chunk partials per row ----------------
__global__ __launch_bounds__(256) void comb_kernel(
    const float* __restrict__ pacc, const float* __restrict__ pm,
    const float* __restrict__ pl, float* __restrict__ out)
{
    const int t = blockIdx.x * 256 + threadIdx.x;
    const int r = t >> 6, dv = t & 63;
    const int strip = r >> 4, qi = r & 15;
    const int base = strip * 128 + qi;
    float mv[8];
    float M = -__builtin_inff();
    #pragma unroll
    for (int cc = 0; cc < 8; ++cc) { mv[cc] = pm[base + cc * 16]; M = fmaxf(M, mv[cc]); }
    float num = 0.f, den = 0.f;
    #pragma unroll
    for (int cc = 0; cc < 8; ++cc) {
        const float wgt = exp2f(mv[cc] - M);
        num += wgt * pacc[(size_t)(base + cc * 16) * 64 + dv];
        den += wgt * pl[base + cc * 16];
    }
    out[t] = num / den;
}

extern "C" void kernel_launch(void* const* d_in, const int* in_sizes, int n_in,
                              void* d_out, int out_size, void* d_ws, size_t ws_size,
                              hipStream_t stream)
{
    const float* Q    = (const float*)d_in[0];
    const float* K    = (const float*)d_in[1];
    const float* V    = (const float*)d_in[2];
    const int*   mask = (const int*)d_in[3];
    const float* Wq   = (const float*)d_in[4];
    const float* bq   = (const float*)d_in[5];
    const float* Wk   = (const float*)d_in[6];
    const float* bk   = (const float*)d_in[7];
    const float* Wv   = (const float*)d_in[8];
    const float* bv   = (const float*)d_in[9];
    float* out = (float*)d_out;

    char* ws = (char*)d_ws;
    u16*   wb   = (u16*)(ws);                            // 384 KB
    u16*   qb   = (u16*)(ws + 393216);                   // 1 MB
    u16*   kb   = (u16*)(ws + 393216 + 1048576);         // 1 MB
    u16*   vtb  = (u16*)(ws + 393216 + 2097152);         // 1 MB
    u64*   bits = (u64*)(ws + 4194304);                  // 4 MB: [8192][16][4] u64
    float* pm   = (float*)(ws + 8388608);                // 256 KB
    float* pl   = (float*)(ws + 8388608 + 262144);       // 256 KB
    float* pacc = (float*)(ws + 8388608 + 524288);       // 16 MB

    wcvt_kernel<<<96, 256, 0, stream>>>(Wq, Wk, Wv, wb);
    fused_kernel<<<3584, 256, 0, stream>>>(Q, K, V, bq, bk, bv, wb, mask,
                                           qb, kb, vtb, bits);
    attn_kernel<<<1024, 256, 0, stream>>>(bits, qb, kb, vtb, pacc, pm, pl);
    comb_kernel<<<2048, 256, 0, stream>>>(pacc, pm, pl, out);
}